// Round 13
// baseline (298.141 us; speedup 1.0000x reference)
//
#include <hip/hip_runtime.h>
#include <math.h>

#define B_ 8
#define N_ 20000
#define K_ 128
#define C_ 256

static_assert(N_ % 32 == 0, "N must be multiple of 32");

constexpr float LMBDA = 100.0f;
constexpr float EPS_EV = 1e-10f;

typedef unsigned int u32x4 __attribute__((ext_vector_type(4)));
typedef short short8_t __attribute__((ext_vector_type(8)));
typedef float f32x4 __attribute__((ext_vector_type(4)));

// Split two fp32 into bf16 hi-plane (truncation; residual exact) and
// bf16 lo-plane (RNE of residual). Packed as (x1|x0) u32 words.
static __device__ inline void split2(float x0, float x1, unsigned& h, unsigned& l) {
  unsigned u0 = __builtin_bit_cast(unsigned, x0);
  unsigned u1 = __builtin_bit_cast(unsigned, x1);
  h = __builtin_amdgcn_perm(u1, u0, 0x07060302u);  // top16(x1)<<16 | top16(x0)
  float r0 = x0 - __builtin_bit_cast(float, u0 & 0xFFFF0000u);  // exact
  float r1 = x1 - __builtin_bit_cast(float, u1 & 0xFFFF0000u);  // exact
  unsigned v0 = __builtin_bit_cast(unsigned, r0);
  unsigned v1 = __builtin_bit_cast(unsigned, r1);
  v0 += 0x7FFFu + ((v0 >> 16) & 1u);  // RNE to bf16
  v1 += 0x7FFFu + ((v1 >> 16) & 1u);
  l = __builtin_amdgcn_perm(v1, v0, 0x07060302u);
}

// publish LDS writes + retire LDS reads, then raw barrier (global prefetch
// loads stay in flight across it -- no vmcnt drain).
#define KFENCE()                                              \
  do {                                                        \
    asm volatile("s_waitcnt lgkmcnt(0)" ::: "memory");        \
    __builtin_amdgcn_sched_barrier(0);                        \
    __builtin_amdgcn_s_barrier();                             \
    __builtin_amdgcn_sched_barrier(0);                        \
  } while (0)

// ---------------------------------------------------------------------------
// Kernel 1: projection GEMM, bf16x3 split MFMA (round-12 structure).
// GRID SWIZZLE: s = blockIdx.x, c0 = blockIdx.y -> the two c-blocks sharing
// an A-slab have linear IDs 32 apart (32%8==0) -> SAME XCD -> A L2-dedup.
// ---------------------------------------------------------------------------
__global__ __launch_bounds__(512, 4)
void proj_mfma(const float* __restrict__ feat_x, const float* __restrict__ feat_y,
               const float* __restrict__ evx, const float* __restrict__ evy,
               float* __restrict__ part, int Sa, int chunk) {
  const int bm = blockIdx.z;
  const int b = bm >> 1, mat = bm & 1;
  const float* __restrict__ E = (mat ? evy : evx) + (size_t)b * K_ * N_;
  const float* __restrict__ F = (mat ? feat_y : feat_x) + (size_t)b * N_ * C_;
  const int c0 = blockIdx.y << 7;          // 2 c-blocks x 128 cols (swizzled)
  const int s = blockIdx.x;
  const int nb = s * chunk;
  const int ne = min(N_, nb + chunk);
  const int nt = (ne - nb) >> 5;

  // B planes: Bh buf p at [p*2048], Bl at [4096 + p*2048]  (32 KB total).
  // Reused post-loop as float[8192] epilogue chunk (128 x 64).
  __shared__ unsigned int BLDS[8192];

  const int t = threadIdx.x;
  const int lane = t & 63, wv = t >> 6;
  const int wm = wv & 3, cw = wv >> 2;     // 4 m-waves x 2 c-halves
  const int lr = lane & 15, lg = lane >> 4;

  // B staging map: col cl, n-octet gh; slot consumed by lane (lr,lg) at ct
  const int cl = t & 127, gh = t >> 7;
  const int sB = ((cl >> 4) << 8) + (gh << 6) + ((cl & 15) << 2);

  // A fragment rows: wm*32 + mt*16 + lr, k-octet lg
  const float* __restrict__ ebase = E + (size_t)((wm << 5) + lr) * N_ + (lg << 3);

  f32x4 acc[2][4];
#pragma unroll
  for (int i = 0; i < 2; ++i)
#pragma unroll
    for (int j = 0; j < 4; ++j) acc[i][j] = (f32x4){0.f, 0.f, 0.f, 0.f};

  float4 Ae[4], Ao[4];
  float pbE[8], pbO[8];

  auto LOADA = [&](float4* A, int n0) {
    const float* ep = ebase + n0;
    A[0] = *(const float4*)ep;
    A[1] = *(const float4*)(ep + 4);
    const float* ep2 = ep + (size_t)16 * N_;
    A[2] = *(const float4*)ep2;
    A[3] = *(const float4*)(ep2 + 4);
  };
  auto LOADB = [&](float* pb, int n0) {
    const float* fp = F + (size_t)(n0 + (gh << 3)) * C_ + c0 + cl;
#pragma unroll
    for (int j = 0; j < 8; ++j) pb[j] = fp[(size_t)j * C_];
  };
  auto WRITEB = [&](int p, const float* pb) {
    unsigned h0, l0, h1, l1, h2, l2, h3, l3;
    split2(pb[0], pb[1], h0, l0);
    split2(pb[2], pb[3], h1, l1);
    split2(pb[4], pb[5], h2, l2);
    split2(pb[6], pb[7], h3, l3);
    *(u32x4*)&BLDS[p * 2048 + sB]        = (u32x4){h0, h1, h2, h3};
    *(u32x4*)&BLDS[4096 + p * 2048 + sB] = (u32x4){l0, l1, l2, l3};
  };
  auto COMPUTE = [&](int p, const float4* A) {
    short8_t ah[2], al[2];
#pragma unroll
    for (int mt = 0; mt < 2; ++mt) {
      unsigned h0, l0, h1, l1, h2, l2, h3, l3;
      split2(A[2 * mt].x, A[2 * mt].y, h0, l0);
      split2(A[2 * mt].z, A[2 * mt].w, h1, l1);
      split2(A[2 * mt + 1].x, A[2 * mt + 1].y, h2, l2);
      split2(A[2 * mt + 1].z, A[2 * mt + 1].w, h3, l3);
      ah[mt] = __builtin_bit_cast(short8_t, (u32x4){h0, h1, h2, h3});
      al[mt] = __builtin_bit_cast(short8_t, (u32x4){l0, l1, l2, l3});
    }
#pragma unroll
    for (int ct8 = 0; ct8 < 4; ++ct8) {
      const int ct = (cw << 2) + ct8;
      const short8_t bh = *(const short8_t*)&BLDS[p * 2048 + (ct << 8) + (lane << 2)];
      const short8_t bl = *(const short8_t*)&BLDS[4096 + p * 2048 + (ct << 8) + (lane << 2)];
#pragma unroll
      for (int mt = 0; mt < 2; ++mt) {
        acc[mt][ct8] = __builtin_amdgcn_mfma_f32_16x16x32_bf16(ah[mt], bh, acc[mt][ct8], 0, 0, 0);
        acc[mt][ct8] = __builtin_amdgcn_mfma_f32_16x16x32_bf16(al[mt], bh, acc[mt][ct8], 0, 0, 0);
        acc[mt][ct8] = __builtin_amdgcn_mfma_f32_16x16x32_bf16(ah[mt], bl, acc[mt][ct8], 0, 0, 0);
      }
    }
  };

  // prologue
  LOADA(Ae, nb);
  LOADB(pbE, nb);
  if (nt > 1) { LOADA(Ao, nb + 32); LOADB(pbO, nb + 32); }
  WRITEB(0, pbE);        // counted wait: tile-0 B loads only
  KFENCE();

  for (int it = 0; it < nt; it += 2) {
    // even step: compute tile it (buf0, Ae); publish tile it+1 into buf1
    if (it + 1 < nt) WRITEB(1, pbO);
    if (it + 2 < nt) LOADB(pbE, nb + ((it + 2) << 5));
    COMPUTE(0, Ae);
    if (it + 2 < nt) LOADA(Ae, nb + ((it + 2) << 5));
    KFENCE();
    if (it + 1 < nt) {
      if (it + 2 < nt) WRITEB(0, pbE);
      if (it + 3 < nt) LOADB(pbO, nb + ((it + 3) << 5));
      COMPUTE(1, Ao);
      if (it + 3 < nt) LOADA(Ao, nb + ((it + 3) << 5));
      KFENCE();
    }
  }

  // ---- epilogue: stage 128x64 f32 chunks in LDS, store full 128B lines ----
  float* cbuf = (float*)BLDS;
  float* __restrict__ P = part + ((size_t)bm * Sa + s) * (K_ * C_);
#pragma unroll
  for (int p2 = 0; p2 < 2; ++p2) {
    __syncthreads();                       // cbuf free (prev pass / last compute)
    if (cw == p2) {
#pragma unroll
      for (int mt = 0; mt < 2; ++mt)
#pragma unroll
        for (int ct8 = 0; ct8 < 4; ++ct8) {
#pragma unroll
          for (int r = 0; r < 4; ++r) {
            const int row = (wm << 5) + (mt << 4) + (lg << 2) + r;
            cbuf[(row << 6) + (ct8 << 4) + lr] = acc[mt][ct8][r];
          }
        }
    }
    __syncthreads();                       // cbuf ready
    const int row = t >> 2, q = t & 3;
    const float* src = &cbuf[(row << 6) + (q << 4)];
    float* dst = P + (size_t)row * C_ + c0 + (p2 << 6) + (q << 4);
    float4 v0 = *(const float4*)(src);
    float4 v1 = *(const float4*)(src + 4);
    float4 v2 = *(const float4*)(src + 8);
    float4 v3 = *(const float4*)(src + 12);
    *(float4*)(dst)      = v0;
    *(float4*)(dst + 4)  = v1;
    *(float4*)(dst + 8)  = v2;
    *(float4*)(dst + 12) = v3;
  }
}

// ---------------------------------------------------------------------------
// Kernel 2: reduce split-n partials -> AB (float4 vectorized)
// ---------------------------------------------------------------------------
__global__ void reduce_parts(const float* __restrict__ part, float* __restrict__ AB, int Sa) {
  const int idx4 = blockIdx.x * 256 + threadIdx.x;       // float4 units
  if (idx4 >= 16 * K_ * C_ / 4) return;
  const int per = K_ * C_ / 4;
  const int bm = idx4 / per;
  const int rem4 = idx4 - bm * per;
  float4 v = {0.f, 0.f, 0.f, 0.f};
  for (int s = 0; s < Sa; ++s) {
    const float4 p = *(const float4*)&part[((size_t)bm * Sa + s) * (K_ * C_) + rem4 * 4];
    v.x += p.x; v.y += p.y; v.z += p.z; v.w += p.w;
  }
  *(float4*)&AB[(size_t)idx4 * 4] = v;
}

// ---------------------------------------------------------------------------
// Kernel 3: gram matrices, 64x64 quadrant per block (8 x 2 x 4 grid).
// which=0: Sm = A A^T + 1e-8 I ; which=1: Rm = Bm A^T
// ---------------------------------------------------------------------------
__global__ __launch_bounds__(256)
void gram_kernel(const float* __restrict__ AB, float* __restrict__ Sm, float* __restrict__ Rm) {
  const int b = blockIdx.x, which = blockIdx.y, qz = blockIdx.z;
  const int iq = (qz & 1) << 6, jq = (qz >> 1) << 6;
  const float* __restrict__ L  = AB + ((size_t)(b * 2 + which)) * (K_ * C_);
  const float* __restrict__ Ar = AB + ((size_t)(b * 2)) * (K_ * C_);
  float* __restrict__ out = (which ? Rm : Sm) + (size_t)b * (K_ * K_);
  const int t = threadIdx.x;
  const int ir = iq + ((t >> 4) << 2), jc = jq + ((t & 15) << 2);
  float acc[4][4] = {};
  for (int c0 = 0; c0 < C_; c0 += 4) {
    float4 li[4], rj[4];
#pragma unroll
    for (int i = 0; i < 4; ++i) li[i] = *(const float4*)(L + (size_t)(ir + i) * C_ + c0);
#pragma unroll
    for (int j = 0; j < 4; ++j) rj[j] = *(const float4*)(Ar + (size_t)(jc + j) * C_ + c0);
#pragma unroll
    for (int i = 0; i < 4; ++i)
#pragma unroll
      for (int j = 0; j < 4; ++j)
        acc[i][j] += li[i].x * rj[j].x + li[i].y * rj[j].y +
                     li[i].z * rj[j].z + li[i].w * rj[j].w;
  }
#pragma unroll
  for (int i = 0; i < 4; ++i)
#pragma unroll
    for (int j = 0; j < 4; ++j) {
      float v = acc[i][j];
      if (!which && (ir + i) == (jc + j)) v += 1e-8f;
      out[(size_t)(ir + i) * K_ + (jc + j)] = v;
    }
}

// ---------------------------------------------------------------------------
// Kernel 4: FUSED mask + blocked Gauss-Jordan inverse + 3 Neumann iters.
// One block per batch (8 x 1024 threads). Sinv lives in LDS a[] the whole
// time; T staged in Tl[]; R and X in registers (static-indexed frags).
// Replaces 5 kernel launches (mask, gj, 3x solve).
// ---------------------------------------------------------------------------
__global__ __launch_bounds__(1024)
void solve_fused(const float* __restrict__ Sm, const float* __restrict__ Rm,
                 const float* __restrict__ evx, const float* __restrict__ evy,
                 float* __restrict__ out) {
  const int b = blockIdx.x, t = threadIdx.x;
  __shared__ float a[K_ * 132];    // S -> Sinv (67.6 KB)
  __shared__ float Tl[K_ * 132];   // gj scratch (Pi/Rp/Cp), then T (67.6 KB)
  __shared__ float pq[512];        // q1,p1,q2,p2

  // ---- mask prep (threads 0..127) ----
  if (t < 128) {
    float e1 = evx[b * K_ + t];
    float e2 = evy[b * K_ + t];
    if (e1 != e1) e1 = EPS_EV;
    if (e2 != e2) e2 = EPS_EV;
    e1 = fminf(fmaxf(e1, EPS_EV), 1e6f);
    e2 = fminf(fmaxf(e2, EPS_EV), 1e6f);
    float v = fmaxf(e1, e2);
#pragma unroll
    for (int d = 1; d < 64; d <<= 1) v = fmaxf(v, __shfl_xor(v, d, 64));
    if ((t & 63) == 0) Tl[t >> 6] = v;
    pq[t] = e1; pq[128 + t] = e2;          // stash clamped evals
  }
  __syncthreads();
  if (t < 128) {
    const float scale = fmaxf(fmaxf(Tl[0], Tl[1]), 1e-10f);
    const float g1 = sqrtf(pq[t] / scale);
    const float g2 = sqrtf(pq[128 + t] / scale);
    const float d1 = fmaf(g1, g1, 1.f);
    const float d2 = fmaf(g2, g2, 1.f);
    pq[t] = g1 / d1;
    pq[128 + t] = 1.f / d1;
    pq[256 + t] = g2 / d2;
    pq[384 + t] = 1.f / d2;
  }

  // ---- load S ----
  const float* __restrict__ Sb = Sm + (size_t)b * (K_ * K_);
#pragma unroll
  for (int l = 0; l < 4; ++l) {
    int f = t + (l << 10);
    int i = f >> 5, j = (f & 31) << 2;
    *(float4*)&a[i * 132 + j] = *(const float4*)(Sb + i * K_ + j);
  }
  __syncthreads();

  // ---- blocked GJ, 1024 threads: j = t&127, rr = t>>7 in [0,8) ----
  float* Pi = &Tl[0];        // 16x20
  float* Rp = &Tl[512];      // 16x132
  float* Cp = &Tl[4096];     // 128x20
  const int j = t & 127, rr = t >> 7;
  const int lane = t & 63;

  for (int p = 0; p < 8; ++p) {
    const int pb = p << 4;

    if (t < 64) {   // ph1: wave 0 inverts 16x16 pivot in registers
      const int r = lane & 15, g = lane >> 4;
      float4 v4 = *(const float4*)&a[(pb + r) * 132 + pb + (g << 2)];
      float vv[4] = {v4.x, v4.y, v4.z, v4.w};
#pragma unroll
      for (int k = 0; k < 16; ++k) {
        const int srcrow = (lane & 48) | k;
        float rk[4];
        rk[0] = __shfl(vv[0], srcrow);
        rk[1] = __shfl(vv[1], srcrow);
        rk[2] = __shfl(vv[2], srcrow);
        rk[3] = __shfl(vv[3], srcrow);
        const int kg = (k >> 2) << 4;
        const float pv = __shfl(vv[k & 3], kg | k);
        const float c  = __shfl(vv[k & 3], kg | r);
        const float pr = 1.0f / pv;
        float rs[4];
#pragma unroll
        for (int e = 0; e < 4; ++e) rs[e] = rk[e] * pr;
        if (r == k) {
#pragma unroll
          for (int e = 0; e < 4; ++e) vv[e] = rs[e];
          if (g == (k >> 2)) vv[k & 3] = pr;
        } else {
#pragma unroll
          for (int e = 0; e < 4; ++e) vv[e] = fmaf(-c, rs[e], vv[e]);
          if (g == (k >> 2)) vv[k & 3] = -c * pr;
        }
      }
      Pi[r * 20 + (g << 2) + 0] = vv[0];
      Pi[r * 20 + (g << 2) + 1] = vv[1];
      Pi[r * 20 + (g << 2) + 2] = vv[2];
      Pi[r * 20 + (g << 2) + 3] = vv[3];
    }
    __syncthreads();

    {  // ph2: Rp = Pinv @ A[p,:]; Cp = A[:,p]
      float Ak[16];
#pragma unroll
      for (int k = 0; k < 16; ++k) Ak[k] = a[(pb + k) * 132 + j];
      const unsigned jj = (unsigned)(j - pb);
#pragma unroll
      for (int q = 0; q < 2; ++q) {
        const int r = (rr << 1) + q;
        float acc = 0.f;
#pragma unroll
        for (int k = 0; k < 16; ++k) acc = fmaf(Pi[r * 20 + k], Ak[k], acc);
        Rp[r * 132 + j] = (jj < 16u) ? Pi[r * 20 + jj] : acc;
      }
      const int i = j;
      const int cb = rr << 1;
      float2 cA = *(const float2*)&a[i * 132 + pb + cb];
      *(float2*)&Cp[i * 20 + cb] = cA;
    }
    __syncthreads();

    {  // ph3: full rank-16 update, 16 rows per group
      float Rk[16];
#pragma unroll
      for (int k = 0; k < 16; ++k) Rk[k] = Rp[k * 132 + j];
      const unsigned jj = (unsigned)(j - pb);
      const int i0 = rr << 4;
#pragma unroll 4
      for (int m = 0; m < 16; ++m) {
        const int i = i0 + m;
        const float4 c0 = *(const float4*)&Cp[i * 20];
        const float4 c1 = *(const float4*)&Cp[i * 20 + 4];
        const float4 c2 = *(const float4*)&Cp[i * 20 + 8];
        const float4 c3 = *(const float4*)&Cp[i * 20 + 12];
        float u0 = c0.x * Rk[0] + c0.y * Rk[1] + c0.z * Rk[2] + c0.w * Rk[3];
        float u1 = c1.x * Rk[4] + c1.y * Rk[5] + c1.z * Rk[6] + c1.w * Rk[7];
        float u2 = c2.x * Rk[8] + c2.y * Rk[9] + c2.z * Rk[10] + c2.w * Rk[11];
        float u3 = c3.x * Rk[12] + c3.y * Rk[13] + c3.z * Rk[14] + c3.w * Rk[15];
        const float upd = (u0 + u1) + (u2 + u3);
        const unsigned ii = (unsigned)(i - pb);
        float newv;
        if (ii < 16u) {
          newv = Rk[ii];
        } else {
          const float base = (jj < 16u) ? 0.f : a[i * 132 + j];
          newv = base - upd;
        }
        a[i * 132 + j] = newv;
      }
    }
    __syncthreads();
  }
  // a[] now holds Sinv. Tl free (last barrier done).

  // ---- Neumann: X = R@Sinv; then twice X = (R - W.*X)@Sinv ----
  const int ir = (t >> 4) << 1;        // row pair
  const int jc = (t & 15) << 3;        // 8-col group
  const float* __restrict__ Rb = Rm + (size_t)b * (K_ * K_);

  float R0[8], R1[8], X0r[8], X1r[8];
  {
    float4 r00 = *(const float4*)(Rb + (size_t)ir * K_ + jc);
    float4 r01 = *(const float4*)(Rb + (size_t)ir * K_ + jc + 4);
    float4 r10 = *(const float4*)(Rb + (size_t)(ir + 1) * K_ + jc);
    float4 r11 = *(const float4*)(Rb + (size_t)(ir + 1) * K_ + jc + 4);
    R0[0]=r00.x; R0[1]=r00.y; R0[2]=r00.z; R0[3]=r00.w;
    R0[4]=r01.x; R0[5]=r01.y; R0[6]=r01.z; R0[7]=r01.w;
    R1[0]=r10.x; R1[1]=r10.y; R1[2]=r10.z; R1[3]=r10.w;
    R1[4]=r11.x; R1[5]=r11.y; R1[6]=r11.z; R1[7]=r11.w;
  }
  const float q2i0 = pq[256 + ir],     p2i0 = pq[384 + ir];
  const float q2i1 = pq[256 + ir + 1], p2i1 = pq[384 + ir + 1];
  float q1j[8], p1j[8];
#pragma unroll
  for (int e = 0; e < 8; ++e) { q1j[e] = pq[jc + e]; p1j[e] = pq[128 + jc + e]; }

  auto MATMUL = [&]() {
    float acc0[8] = {}, acc1[8] = {};
#pragma unroll 4
    for (int k = 0; k < K_; ++k) {
      const float a0 = Tl[(ir + 0) * 132 + k];
      const float a1 = Tl[(ir + 1) * 132 + k];
      const float4 b0 = *(const float4*)&a[k * 132 + jc];
      const float4 b1 = *(const float4*)&a[k * 132 + jc + 4];
      acc0[0] = fmaf(a0, b0.x, acc0[0]); acc0[1] = fmaf(a0, b0.y, acc0[1]);
      acc0[2] = fmaf(a0, b0.z, acc0[2]); acc0[3] = fmaf(a0, b0.w, acc0[3]);
      acc0[4] = fmaf(a0, b1.x, acc0[4]); acc0[5] = fmaf(a0, b1.y, acc0[5]);
      acc0[6] = fmaf(a0, b1.z, acc0[6]); acc0[7] = fmaf(a0, b1.w, acc0[7]);
      acc1[0] = fmaf(a1, b0.x, acc1[0]); acc1[1] = fmaf(a1, b0.y, acc1[1]);
      acc1[2] = fmaf(a1, b0.z, acc1[2]); acc1[3] = fmaf(a1, b0.w, acc1[3]);
      acc1[4] = fmaf(a1, b1.x, acc1[4]); acc1[5] = fmaf(a1, b1.y, acc1[5]);
      acc1[6] = fmaf(a1, b1.z, acc1[6]); acc1[7] = fmaf(a1, b1.w, acc1[7]);
    }
#pragma unroll
    for (int e = 0; e < 8; ++e) { X0r[e] = acc0[e]; X1r[e] = acc1[e]; }
  };

  // iter 1: T = R
#pragma unroll
  for (int e = 0; e < 8; ++e) {
    Tl[(ir + 0) * 132 + jc + e] = R0[e];
    Tl[(ir + 1) * 132 + jc + e] = R1[e];
  }
  __syncthreads();
  MATMUL();

  // iters 2,3: T = R - LMBDA*W.*X
#pragma unroll
  for (int itn = 0; itn < 2; ++itn) {
    __syncthreads();   // all matmul reads of Tl done
#pragma unroll
    for (int e = 0; e < 8; ++e) {
      float dq = q2i0 - q1j[e], dp = p2i0 - p1j[e];
      float w = fmaf(dq, dq, dp * dp);
      Tl[(ir + 0) * 132 + jc + e] = fmaf(-LMBDA * w, X0r[e], R0[e]);
      dq = q2i1 - q1j[e]; dp = p2i1 - p1j[e];
      w = fmaf(dq, dq, dp * dp);
      Tl[(ir + 1) * 132 + jc + e] = fmaf(-LMBDA * w, X1r[e], R1[e]);
    }
    __syncthreads();
    MATMUL();
  }

  // write final X
  float* __restrict__ O = out + (size_t)b * (K_ * K_);
  float4 o;
  o = (float4){X0r[0], X0r[1], X0r[2], X0r[3]}; *(float4*)(O + (size_t)ir * K_ + jc) = o;
  o = (float4){X0r[4], X0r[5], X0r[6], X0r[7]}; *(float4*)(O + (size_t)ir * K_ + jc + 4) = o;
  o = (float4){X1r[0], X1r[1], X1r[2], X1r[3]}; *(float4*)(O + (size_t)(ir + 1) * K_ + jc) = o;
  o = (float4){X1r[4], X1r[5], X1r[6], X1r[7]}; *(float4*)(O + (size_t)(ir + 1) * K_ + jc + 4) = o;
}

// ---------------------------------------------------------------------------
extern "C" void kernel_launch(void* const* d_in, const int* in_sizes, int n_in,
                              void* d_out, int out_size, void* d_ws, size_t ws_size,
                              hipStream_t stream) {
  (void)in_sizes; (void)n_in; (void)out_size;
  const float* feat_x  = (const float*)d_in[0];
  const float* feat_y  = (const float*)d_in[1];
  const float* evals_x = (const float*)d_in[2];
  const float* evals_y = (const float*)d_in[3];
  const float* evtx    = (const float*)d_in[4];
  const float* evty    = (const float*)d_in[5];
  float* out = (float*)d_out;
  float* ws  = (float*)d_ws;

  const size_t KC16 = (size_t)16 * K_ * C_;  // 524288 floats
  const size_t KK   = (size_t)K_ * K_;       // 16384
  const size_t fixed = KC16 + 2 * (KK * B_);
  const int T = N_ / 32;  // 625 k-steps total

  // Sa=32 -> 1024 blocks = 4 blocks/CU. Fallback 16.
  int Sa = ((32 * KC16 + fixed) * sizeof(float) <= ws_size) ? 32 : 16;
  int steps = (T + Sa - 1) / Sa;
  int chunk = steps * 32;
  Sa = (T + steps - 1) / steps;  // active slabs, all with nb < N_

  float* part = ws;
  float* AB   = part + (size_t)Sa * KC16;
  float* Sm   = AB + KC16;
  float* Rm   = Sm + KK * B_;

  proj_mfma<<<dim3(Sa, 2, 16), 512, 0, stream>>>(feat_x, feat_y, evtx, evty, part, Sa, chunk);
  reduce_parts<<<dim3(16 * K_ * C_ / 4 / 256), 256, 0, stream>>>(part, AB, Sa);
  gram_kernel<<<dim3(8, 2, 4), 256, 0, stream>>>(AB, Sm, Rm);
  solve_fused<<<dim3(8), 1024, 0, stream>>>(Sm, Rm, evals_x, evals_y, out);
}

// Round 14
// 252.786 us; speedup vs baseline: 1.1794x; 1.1794x over previous
//
#include <hip/hip_runtime.h>
#include <math.h>

#define B_ 8
#define N_ 20000
#define K_ 128
#define C_ 256

static_assert(N_ % 32 == 0, "N must be multiple of 32");

constexpr float LMBDA = 100.0f;
constexpr float EPS_EV = 1e-10f;

typedef unsigned int u32x4 __attribute__((ext_vector_type(4)));
typedef short short8_t __attribute__((ext_vector_type(8)));
typedef float f32x4 __attribute__((ext_vector_type(4)));

// Split two fp32 into bf16 hi-plane (truncation; residual exact) and
// bf16 lo-plane (RNE of residual). Packed as (x1|x0) u32 words.
static __device__ inline void split2(float x0, float x1, unsigned& h, unsigned& l) {
  unsigned u0 = __builtin_bit_cast(unsigned, x0);
  unsigned u1 = __builtin_bit_cast(unsigned, x1);
  h = __builtin_amdgcn_perm(u1, u0, 0x07060302u);  // top16(x1)<<16 | top16(x0)
  float r0 = x0 - __builtin_bit_cast(float, u0 & 0xFFFF0000u);  // exact
  float r1 = x1 - __builtin_bit_cast(float, u1 & 0xFFFF0000u);  // exact
  unsigned v0 = __builtin_bit_cast(unsigned, r0);
  unsigned v1 = __builtin_bit_cast(unsigned, r1);
  v0 += 0x7FFFu + ((v0 >> 16) & 1u);  // RNE to bf16
  v1 += 0x7FFFu + ((v1 >> 16) & 1u);
  l = __builtin_amdgcn_perm(v1, v0, 0x07060302u);
}

// publish LDS writes + retire LDS reads, then raw barrier (global prefetch
// loads stay in flight across it -- no vmcnt drain).
#define KFENCE()                                              \
  do {                                                        \
    asm volatile("s_waitcnt lgkmcnt(0)" ::: "memory");        \
    __builtin_amdgcn_sched_barrier(0);                        \
    __builtin_amdgcn_s_barrier();                             \
    __builtin_amdgcn_sched_barrier(0);                        \
  } while (0)

// ---------------------------------------------------------------------------
// Kernel 1: projection GEMM, bf16x3 split MFMA (round-6 structure VERBATIM --
// best measured: 161-166us). Double-buffered separate-plane LDS, ONE raw
// barrier per K-step, loads in flight across barriers. B-plane slot swizzle.
// Grid order swapped so the 2 c-blocks sharing an A-slab are Sa apart
// (16%8==0 -> same XCD -> A L2-dedup; FETCH -25% measured round 13).
// ---------------------------------------------------------------------------
__global__ __launch_bounds__(512, 4)
void proj_mfma(const float* __restrict__ feat_x, const float* __restrict__ feat_y,
               const float* __restrict__ evx, const float* __restrict__ evy,
               float* __restrict__ part, int Sa, int chunk) {
  const int bm = blockIdx.z;
  const int b = bm >> 1, mat = bm & 1;
  const float* __restrict__ E = (mat ? evy : evx) + (size_t)b * K_ * N_;
  const float* __restrict__ F = (mat ? feat_y : feat_x) + (size_t)b * N_ * C_;
  const int c0 = blockIdx.y << 7;          // swizzled: y = c-block
  const int s = blockIdx.x;                //           x = slab
  const int nb = s * chunk;
  const int ne = min(N_, nb + chunk);
  const int nt = (ne - nb) >> 5;

  __shared__ unsigned short Ah[2][128][40];
  __shared__ unsigned short Al[2][128][40];
  __shared__ unsigned short Bh[2][128][40];
  __shared__ unsigned short Bl[2][128][40];

  const int t = threadIdx.x;
  const int lane = t & 63, wv = t >> 6;
  const int wm = wv & 3;          // m-tile 0..3 (32 rows each)
  const int wcc = wv >> 2;        // c-tile 0..1 (64 cols each)
  const int lr = lane & 15, lg = lane >> 4;

  // staging maps
  const int am = t >> 2, ak = (t & 3) << 3;      // A: row am, k ak..ak+7
  const int cl = t & 127, gq = (t >> 7) << 2;    // B: col cl, n quads gq, gq+16
  const int sigw = ((cl >> 3) & 3) << 1;         // B write slot swizzle
  const int slotA = ((gq >> 2) ^ sigw) << 2;
  const int slotB = (((gq >> 2) + 4) ^ sigw) << 2;

  f32x4 acc[2][4];
#pragma unroll
  for (int i = 0; i < 2; ++i)
#pragma unroll
    for (int j = 0; j < 4; ++j) acc[i][j] = (f32x4){0.f, 0.f, 0.f, 0.f};

  struct Stage { float4 a0, a1; float b0, b1, b2, b3, b4, b5, b6, b7; };

  auto LOAD = [&](Stage& st, int n0) {
    const float* ep = E + (size_t)am * N_ + n0 + ak;
    st.a0 = *(const float4*)ep;
    st.a1 = *(const float4*)(ep + 4);
    const float* fp = F + (size_t)(n0 + gq) * C_ + c0 + cl;
    st.b0 = fp[0];
    st.b1 = fp[C_];
    st.b2 = fp[2 * C_];
    st.b3 = fp[3 * C_];
    const float* fp2 = fp + (size_t)16 * C_;
    st.b4 = fp2[0];
    st.b5 = fp2[C_];
    st.b6 = fp2[2 * C_];
    st.b7 = fp2[3 * C_];
  };

  auto WRITE = [&](Stage& st, int p) {
    unsigned h01, l01, h23, l23, h45, l45, h67, l67;
    split2(st.a0.x, st.a0.y, h01, l01);
    split2(st.a0.z, st.a0.w, h23, l23);
    split2(st.a1.x, st.a1.y, h45, l45);
    split2(st.a1.z, st.a1.w, h67, l67);
    *(u32x4*)&Ah[p][am][ak] = (u32x4){h01, h23, h45, h67};
    *(u32x4*)&Al[p][am][ak] = (u32x4){l01, l23, l45, l67};
    split2(st.b0, st.b1, h01, l01);
    split2(st.b2, st.b3, h23, l23);
    *(uint2*)&Bh[p][cl][slotA] = (uint2){h01, h23};
    *(uint2*)&Bl[p][cl][slotA] = (uint2){l01, l23};
    split2(st.b4, st.b5, h45, l45);
    split2(st.b6, st.b7, h67, l67);
    *(uint2*)&Bh[p][cl][slotB] = (uint2){h45, h67};
    *(uint2*)&Bl[p][cl][slotB] = (uint2){l45, l67};
  };

  auto COMPUTE = [&](int p) {
    const int k0 = lg << 3;
    short8_t a_h[2], a_l[2];
#pragma unroll
    for (int mt = 0; mt < 2; ++mt) {
      const int m = (wm << 5) + (mt << 4) + lr;
      a_h[mt] = *(const short8_t*)&Ah[p][m][k0];
      a_l[mt] = *(const short8_t*)&Al[p][m][k0];
    }
#pragma unroll
    for (int ct = 0; ct < 4; ++ct) {
      const int c = (wcc << 6) + (ct << 4) + lr;
      const int sig = ((c >> 3) & 3) << 1;
      const int koff = (((lg << 1) ^ sig)) << 2;
      const short8_t b_h = *(const short8_t*)&Bh[p][c][koff];
      const short8_t b_l = *(const short8_t*)&Bl[p][c][koff];
#pragma unroll
      for (int mt = 0; mt < 2; ++mt) {
        acc[mt][ct] = __builtin_amdgcn_mfma_f32_16x16x32_bf16(a_h[mt], b_h, acc[mt][ct], 0, 0, 0);
        acc[mt][ct] = __builtin_amdgcn_mfma_f32_16x16x32_bf16(a_l[mt], b_h, acc[mt][ct], 0, 0, 0);
        acc[mt][ct] = __builtin_amdgcn_mfma_f32_16x16x32_bf16(a_h[mt], b_l, acc[mt][ct], 0, 0, 0);
      }
    }
  };

  Stage sA, sB;
  LOAD(sA, nb);                       // tile 0
  if (nt > 1) LOAD(sB, nb + 32);      // tile 1
  WRITE(sA, 0);                       // waits only tile-0 loads
  KFENCE();

  for (int it = 0; it < nt; it += 2) {
    if (it + 1 < nt) WRITE(sB, 1);                    // vmcnt wait: tile it+1
    if (it + 2 < nt) LOAD(sA, nb + ((it + 2) << 5));  // issued AFTER the wait
    COMPUTE(0);
    KFENCE();
    if (it + 1 < nt) {
      if (it + 2 < nt) WRITE(sA, 0);
      if (it + 3 < nt) LOAD(sB, nb + ((it + 3) << 5));
      COMPUTE(1);
      KFENCE();
    }
  }

  // epilogue: C/D layout col=lane&15, row=(lane>>4)*4+r
  float* __restrict__ P = part + ((size_t)bm * Sa + s) * (K_ * C_);
#pragma unroll
  for (int mt = 0; mt < 2; ++mt)
#pragma unroll
    for (int ct = 0; ct < 4; ++ct) {
      const int ccol = c0 + (wcc << 6) + (ct << 4) + lr;
#pragma unroll
      for (int r = 0; r < 4; ++r) {
        const int mrow = (wm << 5) + (mt << 4) + (lg << 2) + r;
        P[(size_t)mrow * C_ + ccol] = acc[mt][ct][r];
      }
    }
}

// ---------------------------------------------------------------------------
// Kernel 2: reduce split-n partials -> AB (float4 vectorized)
// ---------------------------------------------------------------------------
__global__ void reduce_parts(const float* __restrict__ part, float* __restrict__ AB, int Sa) {
  const int idx4 = blockIdx.x * 256 + threadIdx.x;       // float4 units
  if (idx4 >= 16 * K_ * C_ / 4) return;
  const int per = K_ * C_ / 4;
  const int bm = idx4 / per;
  const int rem4 = idx4 - bm * per;
  float4 v = {0.f, 0.f, 0.f, 0.f};
  for (int s = 0; s < Sa; ++s) {
    const float4 p = *(const float4*)&part[((size_t)bm * Sa + s) * (K_ * C_) + rem4 * 4];
    v.x += p.x; v.y += p.y; v.z += p.z; v.w += p.w;
  }
  *(float4*)&AB[(size_t)idx4 * 4] = v;
}

// ---------------------------------------------------------------------------
// Kernel 3: gram matrices, 64x64 quadrant per block (8 x 2 x 4 grid).
// which=0: Sm = A A^T + 1e-8 I ; which=1: Rm = Bm A^T
// ---------------------------------------------------------------------------
__global__ __launch_bounds__(256)
void gram_kernel(const float* __restrict__ AB, float* __restrict__ Sm, float* __restrict__ Rm) {
  const int b = blockIdx.x, which = blockIdx.y, qz = blockIdx.z;
  const int iq = (qz & 1) << 6, jq = (qz >> 1) << 6;
  const float* __restrict__ L  = AB + ((size_t)(b * 2 + which)) * (K_ * C_);
  const float* __restrict__ Ar = AB + ((size_t)(b * 2)) * (K_ * C_);
  float* __restrict__ out = (which ? Rm : Sm) + (size_t)b * (K_ * K_);
  const int t = threadIdx.x;
  const int ir = iq + ((t >> 4) << 2), jc = jq + ((t & 15) << 2);
  float acc[4][4] = {};
  for (int c0 = 0; c0 < C_; c0 += 4) {
    float4 li[4], rj[4];
#pragma unroll
    for (int i = 0; i < 4; ++i) li[i] = *(const float4*)(L + (size_t)(ir + i) * C_ + c0);
#pragma unroll
    for (int j = 0; j < 4; ++j) rj[j] = *(const float4*)(Ar + (size_t)(jc + j) * C_ + c0);
#pragma unroll
    for (int i = 0; i < 4; ++i)
#pragma unroll
      for (int j = 0; j < 4; ++j)
        acc[i][j] += li[i].x * rj[j].x + li[i].y * rj[j].y +
                     li[i].z * rj[j].z + li[i].w * rj[j].w;
  }
#pragma unroll
  for (int i = 0; i < 4; ++i)
#pragma unroll
    for (int j = 0; j < 4; ++j) {
      float v = acc[i][j];
      if (!which && (ir + i) == (jc + j)) v += 1e-8f;
      out[(size_t)(ir + i) * K_ + (jc + j)] = v;
    }
}

// ---------------------------------------------------------------------------
// Kernel 4: FUSED mask + blocked Gauss-Jordan inverse + 3 Neumann iters.
// (round-13 verbatim -- passed). One block per batch, 1024 threads.
// ---------------------------------------------------------------------------
__global__ __launch_bounds__(1024)
void solve_fused(const float* __restrict__ Sm, const float* __restrict__ Rm,
                 const float* __restrict__ evx, const float* __restrict__ evy,
                 float* __restrict__ out) {
  const int b = blockIdx.x, t = threadIdx.x;
  __shared__ float a[K_ * 132];    // S -> Sinv
  __shared__ float Tl[K_ * 132];   // gj scratch, then T
  __shared__ float pq[512];        // q1,p1,q2,p2

  if (t < 128) {
    float e1 = evx[b * K_ + t];
    float e2 = evy[b * K_ + t];
    if (e1 != e1) e1 = EPS_EV;
    if (e2 != e2) e2 = EPS_EV;
    e1 = fminf(fmaxf(e1, EPS_EV), 1e6f);
    e2 = fminf(fmaxf(e2, EPS_EV), 1e6f);
    float v = fmaxf(e1, e2);
#pragma unroll
    for (int d = 1; d < 64; d <<= 1) v = fmaxf(v, __shfl_xor(v, d, 64));
    if ((t & 63) == 0) Tl[t >> 6] = v;
    pq[t] = e1; pq[128 + t] = e2;
  }
  __syncthreads();
  if (t < 128) {
    const float scale = fmaxf(fmaxf(Tl[0], Tl[1]), 1e-10f);
    const float g1 = sqrtf(pq[t] / scale);
    const float g2 = sqrtf(pq[128 + t] / scale);
    const float d1 = fmaf(g1, g1, 1.f);
    const float d2 = fmaf(g2, g2, 1.f);
    pq[t] = g1 / d1;
    pq[128 + t] = 1.f / d1;
    pq[256 + t] = g2 / d2;
    pq[384 + t] = 1.f / d2;
  }

  const float* __restrict__ Sb = Sm + (size_t)b * (K_ * K_);
#pragma unroll
  for (int l = 0; l < 4; ++l) {
    int f = t + (l << 10);
    int i = f >> 5, j = (f & 31) << 2;
    *(float4*)&a[i * 132 + j] = *(const float4*)(Sb + i * K_ + j);
  }
  __syncthreads();

  float* Pi = &Tl[0];
  float* Rp = &Tl[512];
  float* Cp = &Tl[4096];
  const int j = t & 127, rr = t >> 7;
  const int lane = t & 63;

  for (int p = 0; p < 8; ++p) {
    const int pb = p << 4;

    if (t < 64) {
      const int r = lane & 15, g = lane >> 4;
      float4 v4 = *(const float4*)&a[(pb + r) * 132 + pb + (g << 2)];
      float vv[4] = {v4.x, v4.y, v4.z, v4.w};
#pragma unroll
      for (int k = 0; k < 16; ++k) {
        const int srcrow = (lane & 48) | k;
        float rk[4];
        rk[0] = __shfl(vv[0], srcrow);
        rk[1] = __shfl(vv[1], srcrow);
        rk[2] = __shfl(vv[2], srcrow);
        rk[3] = __shfl(vv[3], srcrow);
        const int kg = (k >> 2) << 4;
        const float pv = __shfl(vv[k & 3], kg | k);
        const float c  = __shfl(vv[k & 3], kg | r);
        const float pr = 1.0f / pv;
        float rs[4];
#pragma unroll
        for (int e = 0; e < 4; ++e) rs[e] = rk[e] * pr;
        if (r == k) {
#pragma unroll
          for (int e = 0; e < 4; ++e) vv[e] = rs[e];
          if (g == (k >> 2)) vv[k & 3] = pr;
        } else {
#pragma unroll
          for (int e = 0; e < 4; ++e) vv[e] = fmaf(-c, rs[e], vv[e]);
          if (g == (k >> 2)) vv[k & 3] = -c * pr;
        }
      }
      Pi[r * 20 + (g << 2) + 0] = vv[0];
      Pi[r * 20 + (g << 2) + 1] = vv[1];
      Pi[r * 20 + (g << 2) + 2] = vv[2];
      Pi[r * 20 + (g << 2) + 3] = vv[3];
    }
    __syncthreads();

    {
      float Ak[16];
#pragma unroll
      for (int k = 0; k < 16; ++k) Ak[k] = a[(pb + k) * 132 + j];
      const unsigned jj = (unsigned)(j - pb);
#pragma unroll
      for (int q = 0; q < 2; ++q) {
        const int r = (rr << 1) + q;
        float acc = 0.f;
#pragma unroll
        for (int k = 0; k < 16; ++k) acc = fmaf(Pi[r * 20 + k], Ak[k], acc);
        Rp[r * 132 + j] = (jj < 16u) ? Pi[r * 20 + jj] : acc;
      }
      const int i = j;
      const int cb = rr << 1;
      float2 cA = *(const float2*)&a[i * 132 + pb + cb];
      *(float2*)&Cp[i * 20 + cb] = cA;
    }
    __syncthreads();

    {
      float Rk[16];
#pragma unroll
      for (int k = 0; k < 16; ++k) Rk[k] = Rp[k * 132 + j];
      const unsigned jj = (unsigned)(j - pb);
      const int i0 = rr << 4;
#pragma unroll 4
      for (int m = 0; m < 16; ++m) {
        const int i = i0 + m;
        const float4 c0 = *(const float4*)&Cp[i * 20];
        const float4 c1 = *(const float4*)&Cp[i * 20 + 4];
        const float4 c2 = *(const float4*)&Cp[i * 20 + 8];
        const float4 c3 = *(const float4*)&Cp[i * 20 + 12];
        float u0 = c0.x * Rk[0] + c0.y * Rk[1] + c0.z * Rk[2] + c0.w * Rk[3];
        float u1 = c1.x * Rk[4] + c1.y * Rk[5] + c1.z * Rk[6] + c1.w * Rk[7];
        float u2 = c2.x * Rk[8] + c2.y * Rk[9] + c2.z * Rk[10] + c2.w * Rk[11];
        float u3 = c3.x * Rk[12] + c3.y * Rk[13] + c3.z * Rk[14] + c3.w * Rk[15];
        const float upd = (u0 + u1) + (u2 + u3);
        const unsigned ii = (unsigned)(i - pb);
        float newv;
        if (ii < 16u) {
          newv = Rk[ii];
        } else {
          const float base = (jj < 16u) ? 0.f : a[i * 132 + j];
          newv = base - upd;
        }
        a[i * 132 + j] = newv;
      }
    }
    __syncthreads();
  }
  // a[] now holds Sinv.

  const int ir = (t >> 4) << 1;
  const int jc = (t & 15) << 3;
  const float* __restrict__ Rb = Rm + (size_t)b * (K_ * K_);

  float R0[8], R1[8], X0r[8], X1r[8];
  {
    float4 r00 = *(const float4*)(Rb + (size_t)ir * K_ + jc);
    float4 r01 = *(const float4*)(Rb + (size_t)ir * K_ + jc + 4);
    float4 r10 = *(const float4*)(Rb + (size_t)(ir + 1) * K_ + jc);
    float4 r11 = *(const float4*)(Rb + (size_t)(ir + 1) * K_ + jc + 4);
    R0[0]=r00.x; R0[1]=r00.y; R0[2]=r00.z; R0[3]=r00.w;
    R0[4]=r01.x; R0[5]=r01.y; R0[6]=r01.z; R0[7]=r01.w;
    R1[0]=r10.x; R1[1]=r10.y; R1[2]=r10.z; R1[3]=r10.w;
    R1[4]=r11.x; R1[5]=r11.y; R1[6]=r11.z; R1[7]=r11.w;
  }
  const float q2i0 = pq[256 + ir],     p2i0 = pq[384 + ir];
  const float q2i1 = pq[256 + ir + 1], p2i1 = pq[384 + ir + 1];
  float q1j[8], p1j[8];
#pragma unroll
  for (int e = 0; e < 8; ++e) { q1j[e] = pq[jc + e]; p1j[e] = pq[128 + jc + e]; }

  auto MATMUL = [&]() {
    float acc0[8] = {}, acc1[8] = {};
#pragma unroll 4
    for (int k = 0; k < K_; ++k) {
      const float a0 = Tl[(ir + 0) * 132 + k];
      const float a1 = Tl[(ir + 1) * 132 + k];
      const float4 b0 = *(const float4*)&a[k * 132 + jc];
      const float4 b1 = *(const float4*)&a[k * 132 + jc + 4];
      acc0[0] = fmaf(a0, b0.x, acc0[0]); acc0[1] = fmaf(a0, b0.y, acc0[1]);
      acc0[2] = fmaf(a0, b0.z, acc0[2]); acc0[3] = fmaf(a0, b0.w, acc0[3]);
      acc0[4] = fmaf(a0, b1.x, acc0[4]); acc0[5] = fmaf(a0, b1.y, acc0[5]);
      acc0[6] = fmaf(a0, b1.z, acc0[6]); acc0[7] = fmaf(a0, b1.w, acc0[7]);
      acc1[0] = fmaf(a1, b0.x, acc1[0]); acc1[1] = fmaf(a1, b0.y, acc1[1]);
      acc1[2] = fmaf(a1, b0.z, acc1[2]); acc1[3] = fmaf(a1, b0.w, acc1[3]);
      acc1[4] = fmaf(a1, b1.x, acc1[4]); acc1[5] = fmaf(a1, b1.y, acc1[5]);
      acc1[6] = fmaf(a1, b1.z, acc1[6]); acc1[7] = fmaf(a1, b1.w, acc1[7]);
    }
#pragma unroll
    for (int e = 0; e < 8; ++e) { X0r[e] = acc0[e]; X1r[e] = acc1[e]; }
  };

  // iter 1: T = R
#pragma unroll
  for (int e = 0; e < 8; ++e) {
    Tl[(ir + 0) * 132 + jc + e] = R0[e];
    Tl[(ir + 1) * 132 + jc + e] = R1[e];
  }
  __syncthreads();
  MATMUL();

  // iters 2,3: T = R - LMBDA*W.*X
#pragma unroll
  for (int itn = 0; itn < 2; ++itn) {
    __syncthreads();
#pragma unroll
    for (int e = 0; e < 8; ++e) {
      float dq = q2i0 - q1j[e], dp = p2i0 - p1j[e];
      float w = fmaf(dq, dq, dp * dp);
      Tl[(ir + 0) * 132 + jc + e] = fmaf(-LMBDA * w, X0r[e], R0[e]);
      dq = q2i1 - q1j[e]; dp = p2i1 - p1j[e];
      w = fmaf(dq, dq, dp * dp);
      Tl[(ir + 1) * 132 + jc + e] = fmaf(-LMBDA * w, X1r[e], R1[e]);
    }
    __syncthreads();
    MATMUL();
  }

  float* __restrict__ O = out + (size_t)b * (K_ * K_);
  float4 o;
  o = (float4){X0r[0], X0r[1], X0r[2], X0r[3]}; *(float4*)(O + (size_t)ir * K_ + jc) = o;
  o = (float4){X0r[4], X0r[5], X0r[6], X0r[7]}; *(float4*)(O + (size_t)ir * K_ + jc + 4) = o;
  o = (float4){X1r[0], X1r[1], X1r[2], X1r[3]}; *(float4*)(O + (size_t)(ir + 1) * K_ + jc) = o;
  o = (float4){X1r[4], X1r[5], X1r[6], X1r[7]}; *(float4*)(O + (size_t)(ir + 1) * K_ + jc + 4) = o;
}

// ---------------------------------------------------------------------------
extern "C" void kernel_launch(void* const* d_in, const int* in_sizes, int n_in,
                              void* d_out, int out_size, void* d_ws, size_t ws_size,
                              hipStream_t stream) {
  (void)in_sizes; (void)n_in; (void)out_size;
  const float* feat_x  = (const float*)d_in[0];
  const float* feat_y  = (const float*)d_in[1];
  const float* evals_x = (const float*)d_in[2];
  const float* evals_y = (const float*)d_in[3];
  const float* evtx    = (const float*)d_in[4];
  const float* evty    = (const float*)d_in[5];
  float* out = (float*)d_out;
  float* ws  = (float*)d_ws;

  const size_t KC16 = (size_t)16 * K_ * C_;  // 524288 floats
  const size_t KK   = (size_t)K_ * K_;       // 16384
  const size_t fixed = KC16 + 2 * (KK * B_);
  const int T = N_ / 32;  // 625 k-steps total

  // Sa=16 -> 512 blocks = 2/CU (best-measured proj config). Fallback 8.
  int Sa = ((16 * KC16 + fixed) * sizeof(float) <= ws_size) ? 16 : 8;
  int steps = (T + Sa - 1) / Sa;
  int chunk = steps * 32;
  Sa = (T + steps - 1) / steps;  // active slabs, all with nb < N_

  float* part = ws;
  float* AB   = part + (size_t)Sa * KC16;
  float* Sm   = AB + KC16;
  float* Rm   = Sm + KK * B_;

  proj_mfma<<<dim3(Sa, 2, 16), 512, 0, stream>>>(feat_x, feat_y, evtx, evty, part, Sa, chunk);
  reduce_parts<<<dim3(16 * K_ * C_ / 4 / 256), 256, 0, stream>>>(part, AB, Sa);
  gram_kernel<<<dim3(8, 2, 4), 256, 0, stream>>>(AB, Sm, Rm);
  solve_fused<<<dim3(8), 1024, 0, stream>>>(Sm, Rm, evals_x, evals_y, out);
}